// Round 9
// baseline (52.871 us; speedup 1.0000x reference)
//
#include <hip/hip_runtime.h>

#define B_DIM 32
#define T_DIM 4096
#define D_DIM 512
#define E_DIM 512
#define EPS_K 1e-7f

typedef float f32x4 __attribute__((ext_vector_type(4)));

// ---------------------------------------------------------------------------
// K1: yp[b,d] = dot(W[d,:], y[b,:])  (yp = y @ W^T), one wave per (b,d).
// ---------------------------------------------------------------------------
__global__ __launch_bounds__(256) void yp_kernel(const float* __restrict__ y,
                                                 const float* __restrict__ W,
                                                 float* __restrict__ yp) {
    const int b    = blockIdx.y;
    const int wave = threadIdx.x >> 6;
    const int lane = threadIdx.x & 63;
    const int d    = blockIdx.x * 4 + wave;

    const float4* Wv = (const float4*)(W + (size_t)d * E_DIM);
    const float4* yv = (const float4*)(y + (size_t)b * E_DIM);
    const float4 w0 = Wv[lane];
    const float4 w1 = Wv[lane + 64];
    const float4 y0 = yv[lane];
    const float4 y1 = yv[lane + 64];

    float p = w0.x*y0.x + w0.y*y0.y + w0.z*y0.z + w0.w*y0.w
            + w1.x*y1.x + w1.y*y1.y + w1.z*y1.z + w1.w*y1.w;
#pragma unroll
    for (int off = 32; off > 0; off >>= 1) p += __shfl_xor(p, off);

    if (lane == 0) yp[(size_t)b * D_DIM + d] = p;
}

// ---------------------------------------------------------------------------
// K2: a_raw[b,t] = exp(tanh(dot(x[b,t,:], yp[b,:]) + bias)) * mask[b,t]
// R8's proven single-purpose streaming body; ONLY change: the 16 x-loads are
// nontemporal (x is 268MB stream-once > L3 -- skip cache allocation).
// ---------------------------------------------------------------------------
__global__ __launch_bounds__(256) void score_kernel(const float* __restrict__ x,
                                                    const float* __restrict__ yp,
                                                    const float* __restrict__ bias,
                                                    const int* __restrict__ mask,
                                                    float* __restrict__ a_raw) {
    const int b    = blockIdx.y;
    const int wave = threadIdx.x >> 6;
    const int lane = threadIdx.x & 63;
    const int t0   = blockIdx.x * 32 + wave * 8;

    // Prefetch independent small loads early (hide under the stream).
    const int mi = mask[(size_t)b * T_DIM + t0 + (lane & 7)];

    const f32x4* ypv = (const f32x4*)(yp + (size_t)b * D_DIM);
    const f32x4 w0 = ypv[lane];
    const f32x4 w1 = ypv[lane + 64];

    const f32x4* xv = (const f32x4*)(x + ((size_t)b * T_DIM + (size_t)t0) * D_DIM);

    // Issue all 16 streaming loads first, nontemporal (nt).
    f32x4 xa[8], xb[8];
#pragma unroll
    for (int i = 0; i < 8; ++i) {
        xa[i] = __builtin_nontemporal_load(xv + i * (D_DIM / 4) + lane);
        xb[i] = __builtin_nontemporal_load(xv + i * (D_DIM / 4) + lane + 64);
    }

    float p[8];
#pragma unroll
    for (int i = 0; i < 8; ++i) {
        p[i] = xa[i][0]*w0[0] + xa[i][1]*w0[1] + xa[i][2]*w0[2] + xa[i][3]*w0[3]
             + xb[i][0]*w1[0] + xb[i][1]*w1[1] + xb[i][2]*w1[2] + xb[i][3]*w1[3];
    }

    // 8 independent butterfly reduces, interleaved per step for ILP.
#pragma unroll
    for (int off = 32; off > 0; off >>= 1) {
#pragma unroll
        for (int i = 0; i < 8; ++i) p[i] += __shfl_xor(p[i], off);
    }

    // Lanes 0..7 finalize row t0+lane (coalesced 32B store).
    if (lane < 8) {
        float s = (lane==0)?p[0]:(lane==1)?p[1]:(lane==2)?p[2]:(lane==3)?p[3]
                :(lane==4)?p[4]:(lane==5)?p[5]:(lane==6)?p[6]:p[7];
        const int t = t0 + lane;
        const float e = expf(tanhf(s + bias[0]));
        a_raw[(size_t)b * T_DIM + t] = mi ? e : 0.f;
    }
}

// ---------------------------------------------------------------------------
// K3: out[b,t] = a_raw[b,t] / (sum_t a_raw[b,:] + EPS)
// grid (4, B), 256 thr; each batch's 4 blocks redundantly compute the batch
// sum with an identical fixed-index tree (deterministic), write their quarter.
// ---------------------------------------------------------------------------
__global__ __launch_bounds__(256) void norm_kernel(const float* __restrict__ a_raw,
                                                   float* __restrict__ out) {
    const int b   = blockIdx.y;
    const int bx  = blockIdx.x;
    const int tid = threadIdx.x;

    const float4* av = (const float4*)(a_raw + (size_t)b * T_DIM);
    float4 v0 = av[tid];
    float4 v1 = av[tid + 256];
    float4 v2 = av[tid + 512];
    float4 v3 = av[tid + 768];

    float s = ((v0.x + v0.y) + (v0.z + v0.w)) + ((v1.x + v1.y) + (v1.z + v1.w))
            + ((v2.x + v2.y) + (v2.z + v2.w)) + ((v3.x + v3.y) + (v3.z + v3.w));
#pragma unroll
    for (int off = 32; off > 0; off >>= 1) s += __shfl_xor(s, off);

    __shared__ float wsum[4];
    __shared__ float inv_s;
    if ((tid & 63) == 0) wsum[tid >> 6] = s;
    __syncthreads();
    if (tid == 0)
        inv_s = 1.0f / (((wsum[0] + wsum[1]) + (wsum[2] + wsum[3])) + EPS_K);
    __syncthreads();
    const float inv = inv_s;

    const float4 v = (bx == 0) ? v0 : (bx == 1) ? v1 : (bx == 2) ? v2 : v3;
    ((float4*)(out + (size_t)b * T_DIM))[bx * 256 + tid] =
        make_float4(v.x * inv, v.y * inv, v.z * inv, v.w * inv);
}

// ---------------------------------------------------------------------------
extern "C" void kernel_launch(void* const* d_in, const int* in_sizes, int n_in,
                              void* d_out, int out_size, void* d_ws, size_t ws_size,
                              hipStream_t stream) {
    const float* x    = (const float*)d_in[0];  // [B,T,D]
    const float* y    = (const float*)d_in[1];  // [B,E]
    const float* W    = (const float*)d_in[2];  // [D,E]
    const float* bias = (const float*)d_in[3];  // [1]
    const int*   mask = (const int*)d_in[4];    // [B,T] (bool -> int32)
    float* out = (float*)d_out;                 // [B,T]

    float* yp    = (float*)d_ws;                // B*D floats = 64 KB
    float* a_raw = yp + B_DIM * D_DIM;          // B*T floats = 512 KB

    yp_kernel<<<dim3(D_DIM / 4, B_DIM), 256, 0, stream>>>(y, W, yp);
    score_kernel<<<dim3(T_DIM / 32, B_DIM), 256, 0, stream>>>(x, yp, bias, mask, a_raw);
    norm_kernel<<<dim3(4, B_DIM), 256, 0, stream>>>(a_raw, out);
}

// Round 10
// 50.849 us; speedup vs baseline: 1.0398x; 1.0398x over previous
//
#include <hip/hip_runtime.h>

#define B_DIM 32
#define T_DIM 4096
#define D_DIM 512
#define E_DIM 512
#define EPS_K 1e-7f

// ---------------------------------------------------------------------------
// K1: yp[b,d] = dot(W[d,:], y[b,:])  (yp = y @ W^T), one wave per (b,d).
// Coalesced float4 loads, 6-step butterfly. (proven R2 version)
// ---------------------------------------------------------------------------
__global__ __launch_bounds__(256) void yp_kernel(const float* __restrict__ y,
                                                 const float* __restrict__ W,
                                                 float* __restrict__ yp) {
    const int b    = blockIdx.y;
    const int wave = threadIdx.x >> 6;
    const int lane = threadIdx.x & 63;
    const int d    = blockIdx.x * 4 + wave;

    const float4* Wv = (const float4*)(W + (size_t)d * E_DIM);
    const float4* yv = (const float4*)(y + (size_t)b * E_DIM);
    const float4 w0 = Wv[lane];
    const float4 w1 = Wv[lane + 64];
    const float4 y0 = yv[lane];
    const float4 y1 = yv[lane + 64];

    float p = w0.x*y0.x + w0.y*y0.y + w0.z*y0.z + w0.w*y0.w
            + w1.x*y1.x + w1.y*y1.y + w1.z*y1.z + w1.w*y1.w;
#pragma unroll
    for (int off = 32; off > 0; off >>= 1) p += __shfl_xor(p, off);

    if (lane == 0) yp[(size_t)b * D_DIM + d] = p;
}

// ---------------------------------------------------------------------------
// K2: a_raw[b,t] = exp(tanh(dot(x[b,t,:], yp[b,:]) + bias)) * mask[b,t]
// Single-purpose streaming kernel (R5/R6/R7: any appended phase collapses
// VGPR allocation to 32-64 and serializes the load batch -> 5x slowdown).
// R9: nontemporal x-loads regressed (+2.2us) -> plain cached loads.
// ---------------------------------------------------------------------------
__global__ __launch_bounds__(256) void score_kernel(const float* __restrict__ x,
                                                    const float* __restrict__ yp,
                                                    const float* __restrict__ bias,
                                                    const int* __restrict__ mask,
                                                    float* __restrict__ a_raw) {
    const int b    = blockIdx.y;
    const int wave = threadIdx.x >> 6;
    const int lane = threadIdx.x & 63;
    const int t0   = blockIdx.x * 32 + wave * 8;

    // Prefetch: independent early loads (mask for this wave's 8 rows, yp).
    const int mi = mask[(size_t)b * T_DIM + t0 + (lane & 7)];

    const float4* ypv = (const float4*)(yp + (size_t)b * D_DIM);
    const float4 w0 = ypv[lane];
    const float4 w1 = ypv[lane + 64];

    const float4* xv = (const float4*)(x + ((size_t)b * T_DIM + (size_t)t0) * D_DIM);

    // Issue all 16 streaming loads first (64 VGPRs of x in flight).
    float4 xa[8], xb[8];
#pragma unroll
    for (int i = 0; i < 8; ++i) {
        xa[i] = xv[i * (D_DIM / 4) + lane];
        xb[i] = xv[i * (D_DIM / 4) + lane + 64];
    }

    float p[8];
#pragma unroll
    for (int i = 0; i < 8; ++i) {
        p[i] = xa[i].x*w0.x + xa[i].y*w0.y + xa[i].z*w0.z + xa[i].w*w0.w
             + xb[i].x*w1.x + xb[i].y*w1.y + xb[i].z*w1.z + xb[i].w*w1.w;
    }

    // 8 independent butterfly reduces, interleaved per step for ILP.
#pragma unroll
    for (int off = 32; off > 0; off >>= 1) {
#pragma unroll
        for (int i = 0; i < 8; ++i) p[i] += __shfl_xor(p[i], off);
    }

    // Lanes 0..7 finalize row t0+lane (coalesced 32B store).
    if (lane < 8) {
        float s = (lane==0)?p[0]:(lane==1)?p[1]:(lane==2)?p[2]:(lane==3)?p[3]
                :(lane==4)?p[4]:(lane==5)?p[5]:(lane==6)?p[6]:p[7];
        const int t = t0 + lane;
        const float e = expf(tanhf(s + bias[0]));
        a_raw[(size_t)b * T_DIM + t] = mi ? e : 0.f;
    }
}

// ---------------------------------------------------------------------------
// K3: out[b,t] = a_raw[b,t] / (sum_t a_raw[b,:] + EPS)
// grid (4, B), 256 thr. Each batch's 4 blocks REDUNDANTLY compute the batch
// sum with an identical fixed-index tree (bitwise-identical inv_s across
// blocks -> deterministic), then each block writes its quarter of the row.
// ---------------------------------------------------------------------------
__global__ __launch_bounds__(256) void norm_kernel(const float* __restrict__ a_raw,
                                                   float* __restrict__ out) {
    const int b   = blockIdx.y;
    const int bx  = blockIdx.x;      // quarter 0..3
    const int tid = threadIdx.x;

    const float4* av = (const float4*)(a_raw + (size_t)b * T_DIM);

    // Every block reads the full row with the same index pattern.
    float4 v0 = av[tid];
    float4 v1 = av[tid + 256];
    float4 v2 = av[tid + 512];
    float4 v3 = av[tid + 768];

    float s = ((v0.x + v0.y) + (v0.z + v0.w)) + ((v1.x + v1.y) + (v1.z + v1.w))
            + ((v2.x + v2.y) + (v2.z + v2.w)) + ((v3.x + v3.y) + (v3.z + v3.w));
#pragma unroll
    for (int off = 32; off > 0; off >>= 1) s += __shfl_xor(s, off);

    __shared__ float wsum[4];
    __shared__ float inv_s;
    const int wave = tid >> 6;
    const int lane = tid & 63;
    if (lane == 0) wsum[wave] = s;
    __syncthreads();
    if (tid == 0)
        inv_s = 1.0f / (((wsum[0] + wsum[1]) + (wsum[2] + wsum[3])) + EPS_K);
    __syncthreads();
    const float inv = inv_s;

    // Write this block's quarter (value already held in registers).
    const float4 v = (bx == 0) ? v0 : (bx == 1) ? v1 : (bx == 2) ? v2 : v3;
    ((float4*)(out + (size_t)b * T_DIM))[bx * 256 + tid] =
        make_float4(v.x * inv, v.y * inv, v.z * inv, v.w * inv);
}

// ---------------------------------------------------------------------------
extern "C" void kernel_launch(void* const* d_in, const int* in_sizes, int n_in,
                              void* d_out, int out_size, void* d_ws, size_t ws_size,
                              hipStream_t stream) {
    const float* x    = (const float*)d_in[0];  // [B,T,D]
    const float* y    = (const float*)d_in[1];  // [B,E]
    const float* W    = (const float*)d_in[2];  // [D,E]
    const float* bias = (const float*)d_in[3];  // [1]
    const int*   mask = (const int*)d_in[4];    // [B,T] (bool -> int32)
    float* out = (float*)d_out;                 // [B,T]

    float* yp    = (float*)d_ws;                // B*D floats = 64 KB
    float* a_raw = yp + B_DIM * D_DIM;          // B*T floats = 512 KB

    yp_kernel<<<dim3(D_DIM / 4, B_DIM), 256, 0, stream>>>(y, W, yp);
    score_kernel<<<dim3(T_DIM / 32, B_DIM), 256, 0, stream>>>(x, yp, bias, mask, a_raw);
    norm_kernel<<<dim3(4, B_DIM), 256, 0, stream>>>(a_raw, out);
}